// Round 11
// baseline (153.006 us; speedup 1.0000x reference)
//
#include <hip/hip_runtime.h>
#include <hip/hip_bf16.h>

#define TT 2048
#define CC 1024
#define DD 128
#define BB 8
#define BK 32
#define NSTEP (CC / BK)   // 32 K-steps

typedef __attribute__((ext_vector_type(8))) short bf16x8;
typedef __attribute__((ext_vector_type(4))) float f32x4;
typedef __attribute__((ext_vector_type(16))) float f32x16;
typedef __attribute__((ext_vector_type(4))) short short4v;

__device__ inline short f2bf(float f) {
    union { float f; unsigned u; } v; v.f = f;
    unsigned r = v.u + 0x7FFFu + ((v.u >> 16) & 1u);   // RNE
    return (short)(r >> 16);
}

__device__ inline unsigned pack2(float lo, float hi) {  // two f32 -> packed bf16x2 word
    return (unsigned)(unsigned short)f2bf(lo) | ((unsigned)(unsigned short)f2bf(hi) << 16);
}

// async global->LDS, 16B per lane (guide §5 / Common-mistake #1)
#define GLOAD16(gp, lp) __builtin_amdgcn_global_load_lds(                       \
    (const __attribute__((address_space(1))) unsigned int*)(const void*)(gp),   \
    (__attribute__((address_space(3))) unsigned int*)(void*)(lp), 16, 0, 0)

// ---------------- Kernel 1: pack Wq|Wk|Wv -> bf16 Wall[384][1024] ----------------
__global__ void prep_w(const float* __restrict__ Wq, const float* __restrict__ Wk,
                       const float* __restrict__ Wv, short* __restrict__ Wall) {
    int row = blockIdx.x;  // 0..383
    const float* src = row < 128 ? Wq + (size_t)row * CC
                     : row < 256 ? Wk + (size_t)(row - 128) * CC
                                 : Wv + (size_t)(row - 256) * CC;
    short* dst = Wall + (size_t)row * CC;
    for (int j = threadIdx.x; j < CC; j += 256) dst[j] = f2bf(src[j]);
}

// ---------------- Kernel 1b: X fp32 -> bf16, streaming ----------------
__global__ __launch_bounds__(256) void xconv(const float* __restrict__ X, short* __restrict__ Xb) {
    size_t i = ((size_t)blockIdx.x * 256 + threadIdx.x) * 8;
    float4 f0 = *(const float4*)(X + i);
    float4 f1 = *(const float4*)(X + i + 4);
    bf16x8 t;
    t[0] = f2bf(f0.x); t[1] = f2bf(f0.y); t[2] = f2bf(f0.z); t[3] = f2bf(f0.w);
    t[4] = f2bf(f1.x); t[5] = f2bf(f1.y); t[6] = f2bf(f1.z); t[7] = f2bf(f1.w);
    *(bf16x8*)(Xb + i) = t;
}

// ---------------- Kernel 2: QKV GEMM, LDS-staged (verified r7) ----------------
__global__ __launch_bounds__(256) void qkv_gemm_lds(const short* __restrict__ Xb,
                                                    const short* __restrict__ Wall,
                                                    short* __restrict__ Q,
                                                    short* __restrict__ K,
                                                    short* __restrict__ Vs) {
    __shared__ char lds[2 * 12288];
    int tid = threadIdx.x, lane = tid & 63, wid = tid >> 6;
    int wm = wid >> 1, wn = wid & 1;
    int lg = lane >> 4, lr = lane & 15;
    int m0 = blockIdx.x * 64;
    int n0 = blockIdx.y * 128;

    int arow = tid >> 2, achk = (tid & 3) * 8;
    const short* gA  = Xb   + (size_t)(m0 + arow) * CC + achk;
    const short* gB0 = Wall + (size_t)(n0 + arow) * CC + achk;
    const short* gB1 = gB0 + (size_t)64 * CC;

    f32x4 acc[2][4] = {};

#define STAGEG(kb, buf) do {                                                    \
        char* base_ = lds + (buf) * 12288;                                      \
        GLOAD16(gA  + (kb), base_ + tid * 16);                                  \
        GLOAD16(gB0 + (kb), base_ + 4096 + tid * 16);                           \
        GLOAD16(gB1 + (kb), base_ + 8192 + tid * 16);                           \
    } while (0)

#define KSTEP(buf) do {                                                         \
        const char* base_ = lds + (buf) * 12288;                                \
        bf16x8 a_[2], b_[4];                                                    \
        _Pragma("unroll")                                                       \
        for (int mi = 0; mi < 2; ++mi)                                          \
            a_[mi] = *(const bf16x8*)(base_ + (wm*32 + mi*16 + lr) * 64 + lg*16);\
        _Pragma("unroll")                                                       \
        for (int nj = 0; nj < 4; ++nj)                                          \
            b_[nj] = *(const bf16x8*)(base_ + 4096 + (wn*64 + nj*16 + lr) * 64 + lg*16);\
        _Pragma("unroll")                                                       \
        for (int mi = 0; mi < 2; ++mi)                                          \
            _Pragma("unroll")                                                   \
            for (int nj = 0; nj < 4; ++nj)                                      \
                acc[mi][nj] = __builtin_amdgcn_mfma_f32_16x16x32_bf16(a_[mi], b_[nj], acc[mi][nj], 0, 0, 0);\
    } while (0)

    STAGEG(0, 0);
#pragma unroll 2
    for (int t = 0; t < NSTEP; ++t) {
        __syncthreads();
        if (t + 1 < NSTEP) STAGEG((t + 1) * BK, (t + 1) & 1);
        KSTEP(t & 1);
    }
#undef STAGEG
#undef KSTEP

    int bidx = m0 >> 11;
    int nt = blockIdx.y;
#pragma unroll
    for (int mi = 0; mi < 2; ++mi) {
        int row = m0 + wm * 32 + mi * 16 + lg * 4;
        int t = row - bidx * TT;
#pragma unroll
        for (int nj = 0; nj < 4; ++nj) {
            int col = wn * 64 + nj * 16 + lr;
            if (nt == 0) {
                short* dst = Q + ((size_t)bidx * TT + t) * DD + col;
#pragma unroll
                for (int r = 0; r < 4; ++r) dst[(size_t)r * DD] = f2bf(acc[mi][nj][r]);
            } else if (nt == 1) {
                short* dst = K + ((size_t)bidx * TT + t) * DD + col;
#pragma unroll
                for (int r = 0; r < 4; ++r) dst[(size_t)r * DD] = f2bf(acc[mi][nj][r]);
            } else {
                short4v v4;
#pragma unroll
                for (int r = 0; r < 4; ++r) v4[r] = f2bf(acc[mi][nj][r]);
                *(short4v*)(Vs + (size_t)bidx * TT * DD
                               + (size_t)(t >> 4) * 2048 + col * 16 + (t & 15)) = v4;
            }
        }
    }
}

// ---------------- Kernel 2b: fallback (fp32 X, direct loads) ----------------
__global__ __launch_bounds__(512) void qkv_gemm(const float* __restrict__ X,
                                                const short* __restrict__ Wall,
                                                short* __restrict__ Q,
                                                short* __restrict__ K,
                                                short* __restrict__ Vs) {
    int tid = threadIdx.x, lane = tid & 63, wid = tid >> 6;
    int wm = wid >> 2, wn = wid & 3;
    int m0 = blockIdx.x * 64 + wm * 32;
    int n0 = wn * 96;
    int lg = lane >> 4, lr = lane & 15;

    f32x4 acc[2][6] = {};

    for (int kb = 0; kb < CC; kb += 32) {
        int kf = kb + lg * 8;
        bf16x8 a[2], bfr[6];
#pragma unroll
        for (int mi = 0; mi < 2; ++mi) {
            const float* p = X + (size_t)(m0 + mi * 16 + lr) * CC + kf;
            float4 f0 = *(const float4*)(p);
            float4 f1 = *(const float4*)(p + 4);
            bf16x8 t;
            t[0] = f2bf(f0.x); t[1] = f2bf(f0.y); t[2] = f2bf(f0.z); t[3] = f2bf(f0.w);
            t[4] = f2bf(f1.x); t[5] = f2bf(f1.y); t[6] = f2bf(f1.z); t[7] = f2bf(f1.w);
            a[mi] = t;
        }
#pragma unroll
        for (int nj = 0; nj < 6; ++nj)
            bfr[nj] = *(const bf16x8*)(Wall + (size_t)(n0 + nj * 16 + lr) * CC + kf);
#pragma unroll
        for (int mi = 0; mi < 2; ++mi)
#pragma unroll
            for (int nj = 0; nj < 6; ++nj)
                acc[mi][nj] = __builtin_amdgcn_mfma_f32_16x16x32_bf16(a[mi], bfr[nj], acc[mi][nj], 0, 0, 0);
    }

    int bidx = (blockIdx.x * 64) / TT;
#pragma unroll
    for (int mi = 0; mi < 2; ++mi) {
        int row = m0 + mi * 16 + lg * 4;
        int t = row - bidx * TT;
#pragma unroll
        for (int nj = 0; nj < 6; ++nj) {
            int col = n0 + nj * 16 + lr;
            if (col < 128) {
                short* dst = Q + ((size_t)bidx * TT + t) * DD + col;
#pragma unroll
                for (int r = 0; r < 4; ++r) dst[(size_t)r * DD] = f2bf(acc[mi][nj][r]);
            } else if (col < 256) {
                short* dst = K + ((size_t)bidx * TT + t) * DD + (col - 128);
#pragma unroll
                for (int r = 0; r < 4; ++r) dst[(size_t)r * DD] = f2bf(acc[mi][nj][r]);
            } else {
                short4v v4;
#pragma unroll
                for (int r = 0; r < 4; ++r) v4[r] = f2bf(acc[mi][nj][r]);
                *(short4v*)(Vs + (size_t)bidx * TT * DD
                               + (size_t)(t >> 4) * 2048 + (col - 256) * 16 + (t & 15)) = v4;
            }
        }
    }
}

// ---------------- shared PV macro (r9-verified) ----------------
#define PV_CHUNK(WS, H, CB) do {                                                   \
    unsigned a0 = WS[4*(H)+0], a1 = WS[4*(H)+1];                                   \
    unsigned b0 = WS[4*(H)+2], b1 = WS[4*(H)+3];                                   \
    unsigned xa0 = (unsigned)__shfl_xor((int)a0, 32, 64);                          \
    unsigned xa1 = (unsigned)__shfl_xor((int)a1, 32, 64);                          \
    unsigned xb0 = (unsigned)__shfl_xor((int)b0, 32, 64);                          \
    unsigned xb1 = (unsigned)__shfl_xor((int)b1, 32, 64);                          \
    union { unsigned u[4]; bf16x8 v; } pu;                                         \
    pu.u[0] = lg2 ? xb0 : a0;                                                      \
    pu.u[1] = lg2 ? xb1 : a1;                                                      \
    pu.u[2] = lg2 ? b0  : xa0;                                                     \
    pu.u[3] = lg2 ? b1  : xa1;                                                     \
    const short* Vp = Vb + ((size_t)((kbase >> 4) + (CB)) * 128 + q) * 16 + lg2 * 8;\
    _Pragma("unroll")                                                              \
    for (int dt = 0; dt < 4; ++dt) {                                               \
        bf16x8 vf = *(const bf16x8*)(Vp + dt * 512);                               \
        acc[dt] = __builtin_amdgcn_mfma_f32_32x32x16_bf16(vf, pu.v, acc[dt], 0,0,0);\
    }                                                                              \
} while (0)

// ---------------- Kernel 3: attention, LDS-staged K, split over key ranges ------
// LDS[r][c] holds K[r][c ^ ((r&15)<<4)] (linear dest + pre-swizzled source, m173).
// Read of global byte-col G of row q therefore uses LDS col G ^ ((q&15)<<4) —
// the XOR must cover the FULL offset incl. kc*32 (r10 bug: add instead of xor).
__global__ __launch_bounds__(256) void attn_split(const short* __restrict__ Q,
                                                  const short* __restrict__ K,
                                                  const short* __restrict__ Vt,
                                                  short* __restrict__ Opart,
                                                  float* __restrict__ mlpart) {
    __shared__ char ldsK[2][16384];   // [buf][64 keys x 256B]

    int tid = threadIdx.x;
    int lane = tid & 63, w = tid >> 6;
    int q = lane & 31, lg2 = lane >> 5;
    int bid = blockIdx.x;
    int b = bid & 7;
    int gs = 71 - (bid >> 3);              // heavy first
    int g = 0, c = 0;
    while (g < 16) { int ns = (g + 2) >> 1; if (gs < c + ns) break; c += ns; ++g; }
    int s = gs - c;
    int ulo = 4 * s;
    int uhi = min(4 * s + 4, 2 * g + 2);
    int NU = uhi - ulo;
    int wr0 = g * 128 + w * 32;
    int qq = wr0 + q;

    const short* Qb = Q + (size_t)b * TT * DD;
    const short* Kb = K + (size_t)b * TT * DD;
    const short* Vb = Vt + (size_t)b * TT * DD;

    // staging: wave w stages rows w*16..w*16+15; dest = w*4096+i*1024+lane*16 (linear)
    int srow0 = w * 16 + (lane >> 4);
    int scolb = (lane & 15) * 16;

#define STAGEK(t_, buf_) do {                                                       \
        int kb_ = (ulo + (t_)) * 64;                                               \
        _Pragma("unroll")                                                          \
        for (int i_ = 0; i_ < 4; ++i_) {                                           \
            int row_ = srow0 + i_ * 4;                                             \
            const char* src_ = (const char*)Kb + (size_t)(kb_ + row_) * 256        \
                               + (scolb ^ ((row_ & 15) << 4));                     \
            GLOAD16(src_, &ldsK[buf_][w * 4096 + i_ * 1024 + (lane & 15) * 16      \
                                      + (lane >> 4) * 256]);                       \
        }                                                                          \
    } while (0)

    bf16x8 qf[8];
#pragma unroll
    for (int kc = 0; kc < 8; ++kc)
        qf[kc] = *(const bf16x8*)(Qb + (size_t)qq * DD + kc * 16 + lg2 * 8);

    f32x16 acc[4] = {};
    float mb = -INFINITY, l = 0.f;
    const float scale = 0.08838834764831845f;

    STAGEK(0, 0);
    for (int t = 0; t < NU; ++t) {
        __syncthreads();                       // staged t visible; reads of t-1 done
        if (t + 1 < NU) STAGEK(t + 1, (t + 1) & 1);
        int kbase = (ulo + t) * 64;
        if (kbase <= wr0) {                    // unit has valid keys for this wave
            const char* Kl = ldsK[t & 1];
            f32x16 s0 = {}, s1 = {};
            int sw = (q & 15) << 4;
            const char* Kq = Kl + q * 256;
#pragma unroll
            for (int kc = 0; kc < 8; ++kc) {
                int ofs = (lg2 * 16 + kc * 32) ^ sw;   // FULL-offset XOR (r10 fix)
                bf16x8 k0 = *(const bf16x8*)(Kq + ofs);
                bf16x8 k1 = *(const bf16x8*)(Kq + 8192 + ofs);
                s0 = __builtin_amdgcn_mfma_f32_32x32x16_bf16(k0, qf[kc], s0, 0, 0, 0);
                s1 = __builtin_amdgcn_mfma_f32_32x32x16_bf16(k1, qf[kc], s1, 0, 0, 0);
            }

            if (kbase + 63 > wr0) {
#pragma unroll
                for (int r = 0; r < 16; ++r) {
                    int kl = (r & 3) + 8 * (r >> 2) + 4 * lg2;
                    s0[r] = (kbase + kl > qq) ? -INFINITY : s0[r] * scale;
                    s1[r] = (kbase + 32 + kl > qq) ? -INFINITY : s1[r] * scale;
                }
            } else {
#pragma unroll
                for (int r = 0; r < 16; ++r) { s0[r] *= scale; s1[r] *= scale; }
            }

            float tmx[16];
#pragma unroll
            for (int r = 0; r < 16; ++r) tmx[r] = fmaxf(s0[r], s1[r]);
#pragma unroll
            for (int st = 8; st; st >>= 1)
#pragma unroll
                for (int r = 0; r < 8; ++r) if (r < st) tmx[r] = fmaxf(tmx[r], tmx[r + st]);
            float pm = fmaxf(tmx[0], __shfl_xor(tmx[0], 32, 64));

            if (__any(pm > mb + 8.f)) {
                float mn = fmaxf(mb, pm);
                float mc = (mn == -INFINITY) ? 0.f : mn;
                float sc = __expf(mb - mc);
                mb = mc; l *= sc;
#pragma unroll
                for (int dt = 0; dt < 4; ++dt)
#pragma unroll
                    for (int r = 0; r < 16; ++r) acc[dt][r] *= sc;
            }

#pragma unroll
            for (int r = 0; r < 16; ++r) { s0[r] = __expf(s0[r] - mb); s1[r] = __expf(s1[r] - mb); }

            float ts[16];
#pragma unroll
            for (int r = 0; r < 16; ++r) ts[r] = s0[r] + s1[r];
#pragma unroll
            for (int st = 8; st; st >>= 1)
#pragma unroll
                for (int r = 0; r < 8; ++r) if (r < st) ts[r] += ts[r + st];
            l += ts[0] + __shfl_xor(ts[0], 32, 64);

            unsigned w0[8], w1[8];
#pragma unroll
            for (int k2 = 0; k2 < 8; ++k2) {
                w0[k2] = pack2(s0[2 * k2], s0[2 * k2 + 1]);
                w1[k2] = pack2(s1[2 * k2], s1[2 * k2 + 1]);
            }

            PV_CHUNK(w0, 0, 0);
            PV_CHUNK(w0, 1, 1);
            PV_CHUNK(w1, 0, 2);
            PV_CHUNK(w1, 1, 3);
        }
    }
#undef STAGEK

    // ---- write partial: O bf16 [row 128][d 128], m/l f32 ----
    int slot = b * 72 + gs;
    short* Op = Opart + (size_t)slot * 16384;
#pragma unroll
    for (int dt = 0; dt < 4; ++dt)
#pragma unroll
        for (int rq = 0; rq < 4; ++rq) {
            short4v v4;
#pragma unroll
            for (int j = 0; j < 4; ++j) v4[j] = f2bf(acc[dt][rq * 4 + j]);
            *(short4v*)(Op + (size_t)(w * 32 + q) * 128 + dt * 32 + rq * 8 + lg2 * 4) = v4;
        }
    if (lg2 == 0) {
        mlpart[(size_t)slot * 256 + w * 32 + q] = (mb == -INFINITY) ? -1e30f : mb;
        mlpart[(size_t)slot * 256 + 128 + w * 32 + q] = l;
    }
}

// ---------------- Kernel 4: combine split partials ----------------
__global__ __launch_bounds__(256) void attn_combine2(const short* __restrict__ Opart,
                                                     const float* __restrict__ mlpart,
                                                     float* __restrict__ out) {
    __shared__ float eL[8][128], invL[128];
    int bid = blockIdx.x;                  // 0..127 = b*16 + g
    int b = bid >> 4, g = bid & 15;
    int S = (g + 2) >> 1;
    int c = 0;
    for (int h = 0; h < g; ++h) c += (h + 2) >> 1;
    int slot0 = b * 72 + c;
    int tid = threadIdx.x;

    if (tid < 128) {
        float M = -INFINITY;
        for (int s = 0; s < S; ++s)
            M = fmaxf(M, mlpart[(size_t)(slot0 + s) * 256 + tid]);
        float L = 0.f;
        for (int s = 0; s < S; ++s) {
            float e = __expf(mlpart[(size_t)(slot0 + s) * 256 + tid] - M);
            eL[s][tid] = e;
            L += mlpart[(size_t)(slot0 + s) * 256 + 128 + tid] * e;
        }
        invL[tid] = 1.f / L;
    }
    __syncthreads();

    float* ob = out + ((size_t)b * TT + g * 128) * DD;
    for (int it = 0; it < 32; ++it) {
        int cell = it * 512 + tid * 2;     // 16384 cells, 2 per thread per iter
        int row = cell >> 7;
        float a0 = 0.f, a1 = 0.f;
        for (int s = 0; s < S; ++s) {
            const unsigned short* p =
                (const unsigned short*)(Opart + (size_t)(slot0 + s) * 16384 + cell);
            union { unsigned u; float f; } v0, v1;
            v0.u = (unsigned)p[0] << 16;
            v1.u = (unsigned)p[1] << 16;
            float e = eL[s][row];
            a0 += v0.f * e; a1 += v1.f * e;
        }
        float inv = invL[row];
        *(float2*)(ob + cell) = make_float2(a0 * inv, a1 * inv);
    }
}

// ---------------- Kernel 3-fallback: r9-verified non-split attention ----------------
__global__ __launch_bounds__(256) void attn32(const short* __restrict__ Q,
                                              const short* __restrict__ K,
                                              const short* __restrict__ Vt,
                                              float* __restrict__ out) {
    __shared__ float slot[2][4][32][33];
    __shared__ float ml[2][2][32];

    int tid = threadIdx.x;
    int lane = tid & 63, w = tid >> 6;
    int q = lane & 31, lg2 = lane >> 5;
    int bid = blockIdx.x;
    int b = bid & 7;
    int qt = 63 - (bid >> 3);
    int r0 = qt * 32;
    int qq = r0 + q;

    const short* Qb = Q + (size_t)b * TT * DD;
    const short* Kb = K + (size_t)b * TT * DD;
    const short* Vb = Vt + (size_t)b * TT * DD;

    bf16x8 qf[8];
#pragma unroll
    for (int kc = 0; kc < 8; ++kc)
        qf[kc] = *(const bf16x8*)(Qb + (size_t)qq * DD + kc * 16 + lg2 * 8);

    f32x16 acc[4] = {};
    float mb = -INFINITY, l = 0.f;
    const float scale = 0.08838834764831845f;
    int kend = r0 + 32;

    for (int kt = w; kt * 64 < kend; kt += 4) {
        int kbase = kt * 64;
        f32x16 s0 = {}, s1 = {};
        const short* Kp0 = Kb + (size_t)(kbase + q) * DD + lg2 * 8;
        const short* Kp1 = Kp0 + (size_t)32 * DD;
#pragma unroll
        for (int kc = 0; kc < 8; ++kc) {
            bf16x8 k0 = *(const bf16x8*)(Kp0 + kc * 16);
            bf16x8 k1 = *(const bf16x8*)(Kp1 + kc * 16);
            s0 = __builtin_amdgcn_mfma_f32_32x32x16_bf16(k0, qf[kc], s0, 0, 0, 0);
            s1 = __builtin_amdgcn_mfma_f32_32x32x16_bf16(k1, qf[kc], s1, 0, 0, 0);
        }

        if (kbase + 63 > r0) {
#pragma unroll
            for (int r = 0; r < 16; ++r) {
                int kl = (r & 3) + 8 * (r >> 2) + 4 * lg2;
                s0[r] = (kbase + kl > qq) ? -INFINITY : s0[r] * scale;
                s1[r] = (kbase + 32 + kl > qq) ? -INFINITY : s1[r] * scale;
            }
        } else {
#pragma unroll
            for (int r = 0; r < 16; ++r) { s0[r] *= scale; s1[r] *= scale; }
        }

        float tmx[16];
#pragma unroll
        for (int r = 0; r < 16; ++r) tmx[r] = fmaxf(s0[r], s1[r]);
#pragma unroll
        for (int st = 8; st; st >>= 1)
#pragma unroll
            for (int r = 0; r < 8; ++r) if (r < st) tmx[r] = fmaxf(tmx[r], tmx[r + st]);
        float pm = fmaxf(tmx[0], __shfl_xor(tmx[0], 32, 64));

        if (__any(pm > mb + 8.f)) {
            float mn = fmaxf(mb, pm);
            float mc = (mn == -INFINITY) ? 0.f : mn;
            float sc = __expf(mb - mc);
            mb = mc; l *= sc;
#pragma unroll
            for (int dt = 0; dt < 4; ++dt)
#pragma unroll
                for (int r = 0; r < 16; ++r) acc[dt][r] *= sc;
        }

#pragma unroll
        for (int r = 0; r < 16; ++r) { s0[r] = __expf(s0[r] - mb); s1[r] = __expf(s1[r] - mb); }

        float ts[16];
#pragma unroll
        for (int r = 0; r < 16; ++r) ts[r] = s0[r] + s1[r];
#pragma unroll
        for (int st = 8; st; st >>= 1)
#pragma unroll
            for (int r = 0; r < 8; ++r) if (r < st) ts[r] += ts[r + st];
        l += ts[0] + __shfl_xor(ts[0], 32, 64);

        unsigned w0[8], w1[8];
#pragma unroll
        for (int k2 = 0; k2 < 8; ++k2) {
            w0[k2] = pack2(s0[2 * k2], s0[2 * k2 + 1]);
            w1[k2] = pack2(s1[2 * k2], s1[2 * k2 + 1]);
        }

        PV_CHUNK(w0, 0, 0);
        PV_CHUNK(w0, 1, 1);
        PV_CHUNK(w1, 0, 2);
        PV_CHUNK(w1, 1, 3);
    }

    if (w >= 2) {
        int s = w - 2;
#pragma unroll
        for (int dt = 0; dt < 4; ++dt)
#pragma unroll
            for (int r = 0; r < 16; ++r)
                slot[s][dt][(r & 3) + 8 * (r >> 2) + 4 * lg2][q] = acc[dt][r];
        if (lg2 == 0) { ml[s][0][q] = mb; ml[s][1][q] = l; }
    }
    __syncthreads();
    if (w < 2) {
        int s = w;
        float m2 = ml[s][0][q], l2 = ml[s][1][q];
        float M = fmaxf(mb, m2);
        float Mc = (M == -INFINITY) ? 0.f : M;
        float e1 = __expf(mb - Mc), e2 = __expf(m2 - Mc);
        mb = Mc; l = l * e1 + l2 * e2;
#pragma unroll
        for (int dt = 0; dt < 4; ++dt)
#pragma unroll
            for (int r = 0; r < 16; ++r)
                acc[dt][r] = acc[dt][r] * e1 + slot[s][dt][(r & 3) + 8 * (r >> 2) + 4 * lg2][q] * e2;
    }
    __syncthreads();
    if (w == 1) {
#pragma unroll
        for (int dt = 0; dt < 4; ++dt)
#pragma unroll
            for (int r = 0; r < 16; ++r)
                slot[0][dt][(r & 3) + 8 * (r >> 2) + 4 * lg2][q] = acc[dt][r];
        if (lg2 == 0) { ml[0][0][q] = mb; ml[0][1][q] = l; }
    }
    __syncthreads();
    if (w == 0) {
        float m2 = ml[0][0][q], l2 = ml[0][1][q];
        float M = fmaxf(mb, m2);
        float Mc = (M == -INFINITY) ? 0.f : M;
        float e1 = __expf(mb - Mc), e2 = __expf(m2 - Mc);
        l = l * e1 + l2 * e2;
        float inv = 1.f / l;
#pragma unroll
        for (int dt = 0; dt < 4; ++dt)
#pragma unroll
            for (int rq = 0; rq < 4; ++rq) {
                f32x4 o4;
#pragma unroll
                for (int j = 0; j < 4; ++j) {
                    int r = rq * 4 + j;
                    o4[j] = (acc[dt][r] * e1 + slot[0][dt][(r & 3) + 8 * rq + 4 * lg2][q] * e2) * inv;
                }
                *(f32x4*)(out + ((size_t)b * TT + qq) * DD + dt * 32 + rq * 8 + lg2 * 4) = o4;
            }
    }
}

extern "C" void kernel_launch(void* const* d_in, const int* in_sizes, int n_in,
                              void* d_out, int out_size, void* d_ws, size_t ws_size,
                              hipStream_t stream) {
    const float* x  = (const float*)d_in[0];
    const float* Wq = (const float*)d_in[1];
    const float* Wk = (const float*)d_in[2];
    const float* Wv = (const float*)d_in[3];
    float* out = (float*)d_out;

    char* ws = (char*)d_ws;
    short* Wall  = (short*)ws;                             //    786,432 B
    short* Q     = (short*)(ws + 786432);                  //  4,194,304 B
    short* K     = (short*)(ws + 786432 + 4194304);
    short* Vs    = (short*)(ws + 786432 + 2 * 4194304);
    short* Xb    = (short*)(ws + 786432 + 3 * 4194304);    // 33,554,432 B
    short* Opart = (short*)(ws + 786432 + 3 * 4194304 + 33554432);      // 18,874,368 B
    float* mlp   = (float*)(ws + 786432 + 3 * 4194304 + 33554432 + 18874368); // 589,824 B
    const size_t need_bf    = 786432 + 3ull * 4194304 + 33554432ull;
    const size_t need_split = need_bf + 18874368ull + 589824ull;       // ~66.4 MB

    prep_w<<<384, 256, 0, stream>>>(Wq, Wk, Wv, Wall);
    if (ws_size >= need_bf) {
        xconv<<<(16777216 / 8) / 256, 256, 0, stream>>>(x, Xb);
        qkv_gemm_lds<<<dim3(256, 3), 256, 0, stream>>>(Xb, Wall, Q, K, Vs);
    } else {
        qkv_gemm<<<16384 / 64, 512, 0, stream>>>(x, Wall, Q, K, Vs);
    }
    if (ws_size >= need_split) {
        attn_split<<<BB * 72, 256, 0, stream>>>(Q, K, Vs, Opart, mlp);
        attn_combine2<<<128, 256, 0, stream>>>(Opart, mlp, out);
    } else {
        attn32<<<BB * 64, 256, 0, stream>>>(Q, K, Vs, out);
    }
}

// Round 12
// 83.804 us; speedup vs baseline: 1.8258x; 1.8258x over previous
//
#include <hip/hip_runtime.h>
#include <hip/hip_bf16.h>

#define TT 2048
#define CC 1024
#define DD 128
#define BB 8
#define BK 32
#define NSTEP (CC / BK)   // 32 K-steps

typedef __attribute__((ext_vector_type(8))) short bf16x8;
typedef __attribute__((ext_vector_type(4))) float f32x4;
typedef __attribute__((ext_vector_type(16))) float f32x16;
typedef __attribute__((ext_vector_type(4))) short short4v;

__device__ inline short f2bf(float f) {
    union { float f; unsigned u; } v; v.f = f;
    unsigned r = v.u + 0x7FFFu + ((v.u >> 16) & 1u);   // RNE
    return (short)(r >> 16);
}

__device__ inline unsigned pack2(float lo, float hi) {  // two f32 -> packed bf16x2 word
    return (unsigned)(unsigned short)f2bf(lo) | ((unsigned)(unsigned short)f2bf(hi) << 16);
}

// async global->LDS, 16B per lane (guide §5 / Common-mistake #1)
#define GLOAD16(gp, lp) __builtin_amdgcn_global_load_lds(                       \
    (const __attribute__((address_space(1))) unsigned int*)(const void*)(gp),   \
    (__attribute__((address_space(3))) unsigned int*)(void*)(lp), 16, 0, 0)

// ---------------- Kernel 1: pack Wq|Wk|Wv -> bf16 Wall[384][1024] (vectorized) ----
__global__ __launch_bounds__(256) void prep_w(const float* __restrict__ Wq,
                                              const float* __restrict__ Wk,
                                              const float* __restrict__ Wv,
                                              short* __restrict__ Wall) {
    int row = blockIdx.x;  // 0..383
    const float* src = row < 128 ? Wq + (size_t)row * CC
                     : row < 256 ? Wk + (size_t)(row - 128) * CC
                                 : Wv + (size_t)(row - 256) * CC;
    short* dst = Wall + (size_t)row * CC;
    int j = threadIdx.x * 4;               // 256 threads x 4 = 1024
    float4 f = *(const float4*)(src + j);
    short4v s = { f2bf(f.x), f2bf(f.y), f2bf(f.z), f2bf(f.w) };
    *(short4v*)(dst + j) = s;
}

// ---------------- Kernel 2: fused QKV GEMM (fp32 X staged, cvt in-register) -------
// C[16384][384] = bf16(X) · Wall^T. Tile 64(M)x128(N), BK=32, 4 waves (2x2).
// A staged as fp32 with XOR-swizzle (row&7)<<4 on the 128B row: linear LDS dest +
// pre-swizzled GLOBAL source (m173); reads use the same full-offset XOR (r10 fix).
// B staged bf16 linear (identical to verified r7 path). V stored tiled
// Vs[b][t>>4][d][t&15] (r9 layout).
__global__ __launch_bounds__(256) void qkv_fused(const float* __restrict__ X,
                                                 const short* __restrict__ Wall,
                                                 short* __restrict__ Q,
                                                 short* __restrict__ K,
                                                 short* __restrict__ Vs) {
    __shared__ char lds[2 * 16384];   // per buf: A fp32 8KB | B bf16 8KB
    int tid = threadIdx.x, lane = tid & 63, wid = tid >> 6;
    int wm = wid >> 1, wn = wid & 1;
    int lg = lane >> 4, lr = lane & 15;
    int m0 = blockIdx.x * 64;
    int n0 = blockIdx.y * 128;

    // A staging: 512 16B-chunks; thread stages chunks tid and tid+256 (rows +32)
    int rA = tid >> 3;                     // 0..31
    int cA = (tid & 7) * 16;               // byte col in 128B row
    int sA = cA ^ ((rA & 7) << 4);         // pre-swizzled source col
    const char* gA0 = (const char*)(X + (size_t)(m0 + rA) * CC) + sA;
    const char* gA1 = (const char*)(X + (size_t)(m0 + rA + 32) * CC) + sA;
    // B staging: 512 16B-chunks linear; rows n0..n0+127
    int rB = tid >> 2, cB = (tid & 3) * 16;
    const char* gB0 = (const char*)(Wall + (size_t)(n0 + rB) * CC) + cB;
    const char* gB1 = (const char*)(Wall + (size_t)(n0 + rB + 64) * CC) + cB;

    f32x4 acc[2][4] = {};

#define STAGEF(t_, buf_) do {                                                   \
        char* b_ = lds + (buf_) * 16384;                                        \
        size_t ka_ = (size_t)(t_) * 128;   /* bytes into fp32 A row */          \
        size_t kb_ = (size_t)(t_) * 64;    /* bytes into bf16 B row */          \
        GLOAD16(gA0 + ka_, b_ + tid * 16);                                      \
        GLOAD16(gA1 + ka_, b_ + 4096 + tid * 16);                               \
        GLOAD16(gB0 + kb_, b_ + 8192 + tid * 16);                               \
        GLOAD16(gB1 + kb_, b_ + 12288 + tid * 16);                              \
    } while (0)

#define KSTEPF(buf_) do {                                                       \
        const char* b_ = lds + (buf_) * 16384;                                  \
        bf16x8 a_[2], bb_[4];                                                   \
        int swz_ = (lr & 7) << 4;                                               \
        _Pragma("unroll")                                                       \
        for (int mi = 0; mi < 2; ++mi) {                                        \
            const char* Ap_ = b_ + (wm * 32 + mi * 16 + lr) * 128;              \
            f32x4 lo_ = *(const f32x4*)(Ap_ + ((lg * 32) ^ swz_));              \
            f32x4 hi_ = *(const f32x4*)(Ap_ + ((lg * 32 + 16) ^ swz_));         \
            bf16x8 t_;                                                          \
            t_[0] = f2bf(lo_[0]); t_[1] = f2bf(lo_[1]);                         \
            t_[2] = f2bf(lo_[2]); t_[3] = f2bf(lo_[3]);                         \
            t_[4] = f2bf(hi_[0]); t_[5] = f2bf(hi_[1]);                         \
            t_[6] = f2bf(hi_[2]); t_[7] = f2bf(hi_[3]);                         \
            a_[mi] = t_;                                                        \
        }                                                                       \
        _Pragma("unroll")                                                       \
        for (int nj = 0; nj < 4; ++nj)                                          \
            bb_[nj] = *(const bf16x8*)(b_ + 8192 + (wn*64 + nj*16 + lr) * 64 + lg*16);\
        _Pragma("unroll")                                                       \
        for (int mi = 0; mi < 2; ++mi)                                          \
            _Pragma("unroll")                                                   \
            for (int nj = 0; nj < 4; ++nj)                                      \
                acc[mi][nj] = __builtin_amdgcn_mfma_f32_16x16x32_bf16(a_[mi], bb_[nj], acc[mi][nj], 0, 0, 0);\
    } while (0)

    STAGEF(0, 0);
#pragma unroll 2
    for (int t = 0; t < NSTEP; ++t) {
        __syncthreads();                   // staged tile t visible; reads of t-1 done
        if (t + 1 < NSTEP) STAGEF(t + 1, (t + 1) & 1);
        KSTEPF(t & 1);
    }
#undef STAGEF
#undef KSTEPF

    int bidx = m0 >> 11;
    int nt = blockIdx.y;
#pragma unroll
    for (int mi = 0; mi < 2; ++mi) {
        int row = m0 + wm * 32 + mi * 16 + lg * 4;
        int t = row - bidx * TT;
#pragma unroll
        for (int nj = 0; nj < 4; ++nj) {
            int col = wn * 64 + nj * 16 + lr;
            if (nt == 0) {
                short* dst = Q + ((size_t)bidx * TT + t) * DD + col;
#pragma unroll
                for (int r = 0; r < 4; ++r) dst[(size_t)r * DD] = f2bf(acc[mi][nj][r]);
            } else if (nt == 1) {
                short* dst = K + ((size_t)bidx * TT + t) * DD + col;
#pragma unroll
                for (int r = 0; r < 4; ++r) dst[(size_t)r * DD] = f2bf(acc[mi][nj][r]);
            } else {
                short4v v4;
#pragma unroll
                for (int r = 0; r < 4; ++r) v4[r] = f2bf(acc[mi][nj][r]);
                *(short4v*)(Vs + (size_t)bidx * TT * DD
                               + (size_t)(t >> 4) * 2048 + col * 16 + (t & 15)) = v4;
            }
        }
    }
}

// ---------------- shared PV macro (r9-verified) ----------------
#define PV_CHUNK(WS, H, CB) do {                                                   \
    unsigned a0 = WS[4*(H)+0], a1 = WS[4*(H)+1];                                   \
    unsigned b0 = WS[4*(H)+2], b1 = WS[4*(H)+3];                                   \
    unsigned xa0 = (unsigned)__shfl_xor((int)a0, 32, 64);                          \
    unsigned xa1 = (unsigned)__shfl_xor((int)a1, 32, 64);                          \
    unsigned xb0 = (unsigned)__shfl_xor((int)b0, 32, 64);                          \
    unsigned xb1 = (unsigned)__shfl_xor((int)b1, 32, 64);                          \
    union { unsigned u[4]; bf16x8 v; } pu;                                         \
    pu.u[0] = lg2 ? xb0 : a0;                                                      \
    pu.u[1] = lg2 ? xb1 : a1;                                                      \
    pu.u[2] = lg2 ? b0  : xa0;                                                     \
    pu.u[3] = lg2 ? b1  : xa1;                                                     \
    const short* Vp = Vb + ((size_t)((kbase >> 4) + (CB)) * 128 + q) * 16 + lg2 * 8;\
    _Pragma("unroll")                                                              \
    for (int dt = 0; dt < 4; ++dt) {                                               \
        bf16x8 vf = *(const bf16x8*)(Vp + dt * 512);                               \
        acc[dt] = __builtin_amdgcn_mfma_f32_32x32x16_bf16(vf, pu.v, acc[dt], 0,0,0);\
    }                                                                              \
} while (0)

// ---------------- Kernel 3: causal flash attention (r9-verified + setprio) -------
__global__ __launch_bounds__(256) void attn32(const short* __restrict__ Q,
                                              const short* __restrict__ K,
                                              const short* __restrict__ Vt,
                                              float* __restrict__ out) {
    __shared__ float slot[2][4][32][33];
    __shared__ float ml[2][2][32];

    int tid = threadIdx.x;
    int lane = tid & 63, w = tid >> 6;
    int q = lane & 31, lg2 = lane >> 5;
    int bid = blockIdx.x;
    int b = bid & 7;
    int qt = 63 - (bid >> 3);
    int r0 = qt * 32;
    int qq = r0 + q;

    const short* Qb = Q + (size_t)b * TT * DD;
    const short* Kb = K + (size_t)b * TT * DD;
    const short* Vb = Vt + (size_t)b * TT * DD;

    bf16x8 qf[8];
#pragma unroll
    for (int kc = 0; kc < 8; ++kc)
        qf[kc] = *(const bf16x8*)(Qb + (size_t)qq * DD + kc * 16 + lg2 * 8);

    f32x16 acc[4] = {};
    float mb = -INFINITY, l = 0.f;
    const float scale = 0.08838834764831845f;
    int kend = r0 + 32;

    for (int kt = w; kt * 64 < kend; kt += 4) {
        int kbase = kt * 64;
        f32x16 s0 = {}, s1 = {};
        const short* Kp0 = Kb + (size_t)(kbase + q) * DD + lg2 * 8;
        const short* Kp1 = Kp0 + (size_t)32 * DD;
        __builtin_amdgcn_s_setprio(1);
#pragma unroll
        for (int kc = 0; kc < 8; ++kc) {
            bf16x8 k0 = *(const bf16x8*)(Kp0 + kc * 16);
            bf16x8 k1 = *(const bf16x8*)(Kp1 + kc * 16);
            s0 = __builtin_amdgcn_mfma_f32_32x32x16_bf16(k0, qf[kc], s0, 0, 0, 0);
            s1 = __builtin_amdgcn_mfma_f32_32x32x16_bf16(k1, qf[kc], s1, 0, 0, 0);
        }
        __builtin_amdgcn_s_setprio(0);

        if (kbase + 63 > r0) {
#pragma unroll
            for (int r = 0; r < 16; ++r) {
                int kl = (r & 3) + 8 * (r >> 2) + 4 * lg2;
                s0[r] = (kbase + kl > qq) ? -INFINITY : s0[r] * scale;
                s1[r] = (kbase + 32 + kl > qq) ? -INFINITY : s1[r] * scale;
            }
        } else {
#pragma unroll
            for (int r = 0; r < 16; ++r) { s0[r] *= scale; s1[r] *= scale; }
        }

        float tmx[16];
#pragma unroll
        for (int r = 0; r < 16; ++r) tmx[r] = fmaxf(s0[r], s1[r]);
#pragma unroll
        for (int st = 8; st; st >>= 1)
#pragma unroll
            for (int r = 0; r < 8; ++r) if (r < st) tmx[r] = fmaxf(tmx[r], tmx[r + st]);
        float pm = fmaxf(tmx[0], __shfl_xor(tmx[0], 32, 64));

        if (__any(pm > mb + 8.f)) {
            float mn = fmaxf(mb, pm);
            float mc = (mn == -INFINITY) ? 0.f : mn;
            float sc = __expf(mb - mc);
            mb = mc; l *= sc;
#pragma unroll
            for (int dt = 0; dt < 4; ++dt)
#pragma unroll
                for (int r = 0; r < 16; ++r) acc[dt][r] *= sc;
        }

#pragma unroll
        for (int r = 0; r < 16; ++r) { s0[r] = __expf(s0[r] - mb); s1[r] = __expf(s1[r] - mb); }

        float ts[16];
#pragma unroll
        for (int r = 0; r < 16; ++r) ts[r] = s0[r] + s1[r];
#pragma unroll
        for (int st = 8; st; st >>= 1)
#pragma unroll
            for (int r = 0; r < 8; ++r) if (r < st) ts[r] += ts[r + st];
        l += ts[0] + __shfl_xor(ts[0], 32, 64);

        unsigned w0[8], w1[8];
#pragma unroll
        for (int k2 = 0; k2 < 8; ++k2) {
            w0[k2] = pack2(s0[2 * k2], s0[2 * k2 + 1]);
            w1[k2] = pack2(s1[2 * k2], s1[2 * k2 + 1]);
        }

        __builtin_amdgcn_s_setprio(1);
        PV_CHUNK(w0, 0, 0);
        PV_CHUNK(w0, 1, 1);
        PV_CHUNK(w1, 0, 2);
        PV_CHUNK(w1, 1, 3);
        __builtin_amdgcn_s_setprio(0);
    }

    if (w >= 2) {
        int s = w - 2;
#pragma unroll
        for (int dt = 0; dt < 4; ++dt)
#pragma unroll
            for (int r = 0; r < 16; ++r)
                slot[s][dt][(r & 3) + 8 * (r >> 2) + 4 * lg2][q] = acc[dt][r];
        if (lg2 == 0) { ml[s][0][q] = mb; ml[s][1][q] = l; }
    }
    __syncthreads();
    if (w < 2) {
        int s = w;
        float m2 = ml[s][0][q], l2 = ml[s][1][q];
        float M = fmaxf(mb, m2);
        float Mc = (M == -INFINITY) ? 0.f : M;
        float e1 = __expf(mb - Mc), e2 = __expf(m2 - Mc);
        mb = Mc; l = l * e1 + l2 * e2;
#pragma unroll
        for (int dt = 0; dt < 4; ++dt)
#pragma unroll
            for (int r = 0; r < 16; ++r)
                acc[dt][r] = acc[dt][r] * e1 + slot[s][dt][(r & 3) + 8 * (r >> 2) + 4 * lg2][q] * e2;
    }
    __syncthreads();
    if (w == 1) {
#pragma unroll
        for (int dt = 0; dt < 4; ++dt)
#pragma unroll
            for (int r = 0; r < 16; ++r)
                slot[0][dt][(r & 3) + 8 * (r >> 2) + 4 * lg2][q] = acc[dt][r];
        if (lg2 == 0) { ml[0][0][q] = mb; ml[0][1][q] = l; }
    }
    __syncthreads();
    if (w == 0) {
        float m2 = ml[0][0][q], l2 = ml[0][1][q];
        float M = fmaxf(mb, m2);
        float Mc = (M == -INFINITY) ? 0.f : M;
        float e1 = __expf(mb - Mc), e2 = __expf(m2 - Mc);
        l = l * e1 + l2 * e2;
        float inv = 1.f / l;
#pragma unroll
        for (int dt = 0; dt < 4; ++dt)
#pragma unroll
            for (int rq = 0; rq < 4; ++rq) {
                f32x4 o4;
#pragma unroll
                for (int j = 0; j < 4; ++j) {
                    int r = rq * 4 + j;
                    o4[j] = (acc[dt][r] * e1 + slot[0][dt][(r & 3) + 8 * rq + 4 * lg2][q] * e2) * inv;
                }
                *(f32x4*)(out + ((size_t)b * TT + qq) * DD + dt * 32 + rq * 8 + lg2 * 4) = o4;
            }
    }
}

extern "C" void kernel_launch(void* const* d_in, const int* in_sizes, int n_in,
                              void* d_out, int out_size, void* d_ws, size_t ws_size,
                              hipStream_t stream) {
    const float* x  = (const float*)d_in[0];
    const float* Wq = (const float*)d_in[1];
    const float* Wk = (const float*)d_in[2];
    const float* Wv = (const float*)d_in[3];
    float* out = (float*)d_out;

    char* ws = (char*)d_ws;
    short* Wall = (short*)ws;                              //   786,432 B
    short* Q    = (short*)(ws + 786432);                   // 4,194,304 B
    short* K    = (short*)(ws + 786432 + 4194304);
    short* Vs   = (short*)(ws + 786432 + 2 * 4194304);     // total ~13.4 MB

    prep_w<<<384, 256, 0, stream>>>(Wq, Wk, Wv, Wall);
    qkv_fused<<<dim3(256, 3), 256, 0, stream>>>(x, Wall, Q, K, Vs);
    attn32<<<BB * 64, 256, 0, stream>>>(Q, K, Vs, out);
}

// Round 13
// 71.258 us; speedup vs baseline: 2.1472x; 1.1761x over previous
//
#include <hip/hip_runtime.h>
#include <hip/hip_bf16.h>

#define TT 2048
#define CC 1024
#define DD 128
#define BB 8
#define BK 32
#define NSTEP (CC / BK)   // 32 K-steps

typedef __attribute__((ext_vector_type(8))) short bf16x8;
typedef __attribute__((ext_vector_type(4))) float f32x4;
typedef __attribute__((ext_vector_type(16))) float f32x16;
typedef __attribute__((ext_vector_type(4))) short short4v;

__device__ inline short f2bf(float f) {
    union { float f; unsigned u; } v; v.f = f;
    unsigned r = v.u + 0x7FFFu + ((v.u >> 16) & 1u);   // RNE
    return (short)(r >> 16);
}

__device__ inline unsigned pack2(float lo, float hi) {  // two f32 -> packed bf16x2 word
    return (unsigned)(unsigned short)f2bf(lo) | ((unsigned)(unsigned short)f2bf(hi) << 16);
}

// async global->LDS, 16B per lane (guide §5 / Common-mistake #1)
#define GLOAD16(gp, lp) __builtin_amdgcn_global_load_lds(                       \
    (const __attribute__((address_space(1))) unsigned int*)(const void*)(gp),   \
    (__attribute__((address_space(3))) unsigned int*)(void*)(lp), 16, 0, 0)

// ---------------- Kernel 1: pack Wq|Wk|Wv -> bf16 Wall[384][1024] ----------------
__global__ __launch_bounds__(256) void prep_w(const float* __restrict__ Wq,
                                              const float* __restrict__ Wk,
                                              const float* __restrict__ Wv,
                                              short* __restrict__ Wall) {
    int row = blockIdx.x;  // 0..383
    const float* src = row < 128 ? Wq + (size_t)row * CC
                     : row < 256 ? Wk + (size_t)(row - 128) * CC
                                 : Wv + (size_t)(row - 256) * CC;
    short* dst = Wall + (size_t)row * CC;
    int j = threadIdx.x * 4;
    float4 f = *(const float4*)(src + j);
    short4v s = { f2bf(f.x), f2bf(f.y), f2bf(f.z), f2bf(f.w) };
    *(short4v*)(dst + j) = s;
}

// ---------------- Kernel 2: ONE-PASS fused QKV GEMM ----------------
// C[16384][384] = bf16(X)·Wall^T in a single column pass: X read ONCE (~64MB vs
// 192MB for 3 col-tiles). Tile 64(M)x384(N), BK=32, 8 waves (2x4; wave = 32x96).
// A staged fp32 with (row&7)<<4 XOR-swizzle: linear LDS dest + pre-swizzled global
// source; reads XOR the FULL offset (r10 lesson). B staged bf16 linear.
// V stored tiled Vs[b][t>>4][d][t&15] (r9 layout).
__global__ __launch_bounds__(512) void qkv_onepass(const float* __restrict__ X,
                                                   const short* __restrict__ Wall,
                                                   short* __restrict__ Q,
                                                   short* __restrict__ K,
                                                   short* __restrict__ Vs) {
    __shared__ char lds[2 * 32768];   // per buf: A fp32 8KB | B bf16 24KB
    int tid = threadIdx.x, lane = tid & 63, wid = tid >> 6;
    int wm = wid >> 2, wn = wid & 3;       // 2 x 4 wave grid
    int lg = lane >> 4, lr = lane & 15;
    int m0 = blockIdx.x * 64;

    // A staging: 512 16B-chunks (64 rows x 8), thread -> chunk tid
    int rA = tid >> 3, cA = (tid & 7) * 16;
    int sA = cA ^ ((rA & 7) << 4);                      // pre-swizzled source col
    const char* gA = (const char*)(X + (size_t)(m0 + rA) * CC) + sA;
    // B staging: 1536 16B-chunks (384 rows x 4), thread -> chunks tid + i*512
    int rB0 = tid >> 2, cB = (tid & 3) * 16;
    const char* gB = (const char*)Wall + cB;

    f32x4 acc[2][6] = {};

#define STAGE1(t_, buf_) do {                                                   \
        char* b_ = lds + (buf_) * 32768;                                        \
        GLOAD16(gA + (size_t)(t_) * 128, b_ + tid * 16);                        \
        _Pragma("unroll")                                                       \
        for (int i_ = 0; i_ < 3; ++i_)                                          \
            GLOAD16(gB + (size_t)(rB0 + i_ * 128) * 2048 + (size_t)(t_) * 64,   \
                    b_ + 8192 + (tid + i_ * 512) * 16);                         \
    } while (0)

#define KSTEP1(buf_) do {                                                       \
        const char* b_ = lds + (buf_) * 32768;                                  \
        bf16x8 a_[2], bb_[6];                                                   \
        int swz_ = (lr & 7) << 4;                                               \
        _Pragma("unroll")                                                       \
        for (int mi = 0; mi < 2; ++mi) {                                        \
            const char* Ap_ = b_ + (wm * 32 + mi * 16 + lr) * 128;              \
            f32x4 lo_ = *(const f32x4*)(Ap_ + ((lg * 32) ^ swz_));              \
            f32x4 hi_ = *(const f32x4*)(Ap_ + ((lg * 32 + 16) ^ swz_));         \
            bf16x8 t_;                                                          \
            t_[0] = f2bf(lo_[0]); t_[1] = f2bf(lo_[1]);                         \
            t_[2] = f2bf(lo_[2]); t_[3] = f2bf(lo_[3]);                         \
            t_[4] = f2bf(hi_[0]); t_[5] = f2bf(hi_[1]);                         \
            t_[6] = f2bf(hi_[2]); t_[7] = f2bf(hi_[3]);                         \
            a_[mi] = t_;                                                        \
        }                                                                       \
        _Pragma("unroll")                                                       \
        for (int nj = 0; nj < 6; ++nj)                                          \
            bb_[nj] = *(const bf16x8*)(b_ + 8192 + (wn*96 + nj*16 + lr) * 64 + lg*16);\
        _Pragma("unroll")                                                       \
        for (int mi = 0; mi < 2; ++mi)                                          \
            _Pragma("unroll")                                                   \
            for (int nj = 0; nj < 6; ++nj)                                      \
                acc[mi][nj] = __builtin_amdgcn_mfma_f32_16x16x32_bf16(a_[mi], bb_[nj], acc[mi][nj], 0, 0, 0);\
    } while (0)

    STAGE1(0, 0);
#pragma unroll 2
    for (int t = 0; t < NSTEP; ++t) {
        __syncthreads();                   // staged tile t visible; reads of t-1 done
        if (t + 1 < NSTEP) STAGE1(t + 1, (t + 1) & 1);
        KSTEP1(t & 1);
    }
#undef STAGE1
#undef KSTEP1

    int bidx = m0 >> 11;
#pragma unroll
    for (int mi = 0; mi < 2; ++mi) {
        int row = m0 + wm * 32 + mi * 16 + lg * 4;
        int t = row - bidx * TT;
#pragma unroll
        for (int nj = 0; nj < 6; ++nj) {
            int col = wn * 96 + nj * 16 + lr;          // 0..383, uniform per (wn,nj)
            if (col < 128) {
                short* dst = Q + ((size_t)bidx * TT + t) * DD + col;
#pragma unroll
                for (int r = 0; r < 4; ++r) dst[(size_t)r * DD] = f2bf(acc[mi][nj][r]);
            } else if (col < 256) {
                short* dst = K + ((size_t)bidx * TT + t) * DD + (col - 128);
#pragma unroll
                for (int r = 0; r < 4; ++r) dst[(size_t)r * DD] = f2bf(acc[mi][nj][r]);
            } else {
                short4v v4;
#pragma unroll
                for (int r = 0; r < 4; ++r) v4[r] = f2bf(acc[mi][nj][r]);
                *(short4v*)(Vs + (size_t)bidx * TT * DD
                               + (size_t)(t >> 4) * 2048 + (col - 256) * 16 + (t & 15)) = v4;
            }
        }
    }
}

// ---------------- PV macro: uses preloaded V fragments ----------------
#define PV_CHUNK(WS, H, CB) do {                                                   \
    unsigned a0 = WS[4*(H)+0], a1 = WS[4*(H)+1];                                   \
    unsigned b0 = WS[4*(H)+2], b1 = WS[4*(H)+3];                                   \
    unsigned xa0 = (unsigned)__shfl_xor((int)a0, 32, 64);                          \
    unsigned xa1 = (unsigned)__shfl_xor((int)a1, 32, 64);                          \
    unsigned xb0 = (unsigned)__shfl_xor((int)b0, 32, 64);                          \
    unsigned xb1 = (unsigned)__shfl_xor((int)b1, 32, 64);                          \
    union { unsigned u[4]; bf16x8 v; } pu;                                         \
    pu.u[0] = lg2 ? xb0 : a0;                                                      \
    pu.u[1] = lg2 ? xb1 : a1;                                                      \
    pu.u[2] = lg2 ? b0  : xa0;                                                     \
    pu.u[3] = lg2 ? b1  : xa1;                                                     \
    _Pragma("unroll")                                                              \
    for (int dt = 0; dt < 4; ++dt)                                                 \
        acc[dt] = __builtin_amdgcn_mfma_f32_32x32x16_bf16(vf[CB][dt], pu.v, acc[dt], 0,0,0);\
} while (0)

// ---------------- Kernel 3: causal flash attention (r9-verified + V preload) -----
__global__ __launch_bounds__(256) void attn32(const short* __restrict__ Q,
                                              const short* __restrict__ K,
                                              const short* __restrict__ Vt,
                                              float* __restrict__ out) {
    __shared__ float slot[2][4][32][33];
    __shared__ float ml[2][2][32];

    int tid = threadIdx.x;
    int lane = tid & 63, w = tid >> 6;
    int q = lane & 31, lg2 = lane >> 5;
    int bid = blockIdx.x;
    int b = bid & 7;
    int qt = 63 - (bid >> 3);
    int r0 = qt * 32;
    int qq = r0 + q;

    const short* Qb = Q + (size_t)b * TT * DD;
    const short* Kb = K + (size_t)b * TT * DD;
    const short* Vb = Vt + (size_t)b * TT * DD;

    bf16x8 qf[8];
#pragma unroll
    for (int kc = 0; kc < 8; ++kc)
        qf[kc] = *(const bf16x8*)(Qb + (size_t)qq * DD + kc * 16 + lg2 * 8);

    f32x16 acc[4] = {};
    float mb = -INFINITY, l = 0.f;
    const float scale = 0.08838834764831845f;
    int kend = r0 + 32;

    for (int kt = w; kt * 64 < kend; kt += 4) {
        int kbase = kt * 64;
        f32x16 s0 = {}, s1 = {};
        const short* Kp0 = Kb + (size_t)(kbase + q) * DD + lg2 * 8;
        const short* Kp1 = Kp0 + (size_t)32 * DD;
#pragma unroll
        for (int kc = 0; kc < 8; ++kc) {
            bf16x8 k0 = *(const bf16x8*)(Kp0 + kc * 16);
            bf16x8 k1 = *(const bf16x8*)(Kp1 + kc * 16);
            s0 = __builtin_amdgcn_mfma_f32_32x32x16_bf16(k0, qf[kc], s0, 0, 0, 0);
            s1 = __builtin_amdgcn_mfma_f32_32x32x16_bf16(k1, qf[kc], s1, 0, 0, 0);
        }

        // V preload: addresses independent of softmax -> latency hides under it
        bf16x8 vf[4][4];
#pragma unroll
        for (int cb = 0; cb < 4; ++cb) {
            const short* Vp = Vb + ((size_t)((kbase >> 4) + cb) * 128 + q) * 16 + lg2 * 8;
#pragma unroll
            for (int dt = 0; dt < 4; ++dt)
                vf[cb][dt] = *(const bf16x8*)(Vp + dt * 512);
        }

        if (kbase + 63 > r0) {
#pragma unroll
            for (int r = 0; r < 16; ++r) {
                int kl = (r & 3) + 8 * (r >> 2) + 4 * lg2;
                s0[r] = (kbase + kl > qq) ? -INFINITY : s0[r] * scale;
                s1[r] = (kbase + 32 + kl > qq) ? -INFINITY : s1[r] * scale;
            }
        } else {
#pragma unroll
            for (int r = 0; r < 16; ++r) { s0[r] *= scale; s1[r] *= scale; }
        }

        float tmx[16];
#pragma unroll
        for (int r = 0; r < 16; ++r) tmx[r] = fmaxf(s0[r], s1[r]);
#pragma unroll
        for (int st = 8; st; st >>= 1)
#pragma unroll
            for (int r = 0; r < 8; ++r) if (r < st) tmx[r] = fmaxf(tmx[r], tmx[r + st]);
        float pm = fmaxf(tmx[0], __shfl_xor(tmx[0], 32, 64));

        if (__any(pm > mb + 8.f)) {
            float mn = fmaxf(mb, pm);
            float mc = (mn == -INFINITY) ? 0.f : mn;
            float sc = __expf(mb - mc);
            mb = mc; l *= sc;
#pragma unroll
            for (int dt = 0; dt < 4; ++dt)
#pragma unroll
                for (int r = 0; r < 16; ++r) acc[dt][r] *= sc;
        }

#pragma unroll
        for (int r = 0; r < 16; ++r) { s0[r] = __expf(s0[r] - mb); s1[r] = __expf(s1[r] - mb); }

        float ts[16];
#pragma unroll
        for (int r = 0; r < 16; ++r) ts[r] = s0[r] + s1[r];
#pragma unroll
        for (int st = 8; st; st >>= 1)
#pragma unroll
            for (int r = 0; r < 8; ++r) if (r < st) ts[r] += ts[r + st];
        l += ts[0] + __shfl_xor(ts[0], 32, 64);

        unsigned w0[8], w1[8];
#pragma unroll
        for (int k2 = 0; k2 < 8; ++k2) {
            w0[k2] = pack2(s0[2 * k2], s0[2 * k2 + 1]);
            w1[k2] = pack2(s1[2 * k2], s1[2 * k2 + 1]);
        }

        PV_CHUNK(w0, 0, 0);
        PV_CHUNK(w0, 1, 1);
        PV_CHUNK(w1, 0, 2);
        PV_CHUNK(w1, 1, 3);
    }

    if (w >= 2) {
        int s = w - 2;
#pragma unroll
        for (int dt = 0; dt < 4; ++dt)
#pragma unroll
            for (int r = 0; r < 16; ++r)
                slot[s][dt][(r & 3) + 8 * (r >> 2) + 4 * lg2][q] = acc[dt][r];
        if (lg2 == 0) { ml[s][0][q] = mb; ml[s][1][q] = l; }
    }
    __syncthreads();
    if (w < 2) {
        int s = w;
        float m2 = ml[s][0][q], l2 = ml[s][1][q];
        float M = fmaxf(mb, m2);
        float Mc = (M == -INFINITY) ? 0.f : M;
        float e1 = __expf(mb - Mc), e2 = __expf(m2 - Mc);
        mb = Mc; l = l * e1 + l2 * e2;
#pragma unroll
        for (int dt = 0; dt < 4; ++dt)
#pragma unroll
            for (int r = 0; r < 16; ++r)
                acc[dt][r] = acc[dt][r] * e1 + slot[s][dt][(r & 3) + 8 * (r >> 2) + 4 * lg2][q] * e2;
    }
    __syncthreads();
    if (w == 1) {
#pragma unroll
        for (int dt = 0; dt < 4; ++dt)
#pragma unroll
            for (int r = 0; r < 16; ++r)
                slot[0][dt][(r & 3) + 8 * (r >> 2) + 4 * lg2][q] = acc[dt][r];
        if (lg2 == 0) { ml[0][0][q] = mb; ml[0][1][q] = l; }
    }
    __syncthreads();
    if (w == 0) {
        float m2 = ml[0][0][q], l2 = ml[0][1][q];
        float M = fmaxf(mb, m2);
        float Mc = (M == -INFINITY) ? 0.f : M;
        float e1 = __expf(mb - Mc), e2 = __expf(m2 - Mc);
        l = l * e1 + l2 * e2;
        float inv = 1.f / l;
#pragma unroll
        for (int dt = 0; dt < 4; ++dt)
#pragma unroll
            for (int rq = 0; rq < 4; ++rq) {
                f32x4 o4;
#pragma unroll
                for (int j = 0; j < 4; ++j) {
                    int r = rq * 4 + j;
                    o4[j] = (acc[dt][r] * e1 + slot[0][dt][(r & 3) + 8 * rq + 4 * lg2][q] * e2) * inv;
                }
                *(f32x4*)(out + ((size_t)b * TT + qq) * DD + dt * 32 + rq * 8 + lg2 * 4) = o4;
            }
    }
}

extern "C" void kernel_launch(void* const* d_in, const int* in_sizes, int n_in,
                              void* d_out, int out_size, void* d_ws, size_t ws_size,
                              hipStream_t stream) {
    const float* x  = (const float*)d_in[0];
    const float* Wq = (const float*)d_in[1];
    const float* Wk = (const float*)d_in[2];
    const float* Wv = (const float*)d_in[3];
    float* out = (float*)d_out;

    char* ws = (char*)d_ws;
    short* Wall = (short*)ws;                              //   786,432 B
    short* Q    = (short*)(ws + 786432);                   // 4,194,304 B
    short* K    = (short*)(ws + 786432 + 4194304);
    short* Vs   = (short*)(ws + 786432 + 2 * 4194304);     // total ~13.4 MB

    prep_w<<<384, 256, 0, stream>>>(Wq, Wk, Wv, Wall);
    qkv_onepass<<<256, 512, 0, stream>>>(x, Wall, Q, K, Vs);
    attn32<<<BB * 64, 256, 0, stream>>>(Q, K, Vs, out);
}